// Round 3
// baseline (356.943 us; speedup 1.0000x reference)
//
#include <hip/hip_runtime.h>

namespace {

constexpr float kAlpha = 0.025f;
constexpr float kC1 = 1.0e-4f;  // (0.01*1)^2
constexpr float kC2 = 9.0e-4f;  // (0.03*1)^2

constexpr int SXS = 68;  // patch row stride: 68*4B=272B, 16B-aligned rows,
                         // quad-bank offset 17 mod 8 = 1 per row -> uniform
constexpr int HBS = 32;  // hb row stride (128B, quad-bank = colgroup)

// LDS: 2*64*68*4 = 34.8 KB patches + 5*64*32*4 = 40 KB hb = ~75.5 KB
// -> 2 blocks/CU
struct Smem {
  float sx[64 * SXS];
  float sy[64 * SXS];
  float hb[5][64 * HBS];  // maps: 0=x, 1=y, 2=x^2+y^2, 3=xy, 4=|x-y| (last)
  float g1[5 * 33];
  float red[4];
};

__device__ __forceinline__ float rfl(float v) {
  return __uint_as_float(__builtin_amdgcn_readfirstlane(__float_as_uint(v)));
}

// One sigma.
//  H: 256 thr stream float4 windows -> 4(5) maps, b128 writes to hb.
//  V: thread=(map,8-row strip,4-col grp) streams b128 down columns-of-4,
//     writes results back into hb rows 0..31 (dead after B3).
//  C: 128 thr (col, 8-row strip) scalar-read 4(5) maps, update Pcs/lum/l1.
template <int R, bool LAST>
__device__ __forceinline__ void process_sigma(Smem& sm, int s, int tid,
                                              float Pcs[8], float lumP[8],
                                              float l1v[8]) {
  constexpr int T = 2 * R + 1;
  constexpr int NMAP = LAST ? 5 : 4;

  __syncthreads();  // B1: prev combine reads done; g1/patch ready (sigma 0)

  float gs[T];  // wave-uniform -> SGPRs
  {
    const float* gb = sm.g1 + s * 33 + (16 - R);
#pragma unroll
    for (int j = 0; j < T; ++j) gs[j] = rfl(gb[j]);
  }

  // ---- H: rows [16-R, 48+R), 32 cols, float4-streamed windows ----
  constexpr int ROWS = 32 + 2 * R;
  constexpr int LO = (16 - R) & ~3;        // aligned window start (col offset)
  constexpr int D = (16 - R) - LO;         // 0..3
  constexpr int NC = (19 + R - LO) / 4 + 1;  // float4 chunks per window
  for (int idx = tid; idx < ROWS * 8; idx += 256) {
    const int pr = (16 - R) + (idx >> 3);
    const int c0 = (idx & 7) << 2;
    const float* bx = sm.sx + pr * SXS + c0 + LO;
    const float* by = sm.sy + pr * SXS + c0 + LO;
    float ax[4] = {0.f, 0.f, 0.f, 0.f};
    float ay[4] = {0.f, 0.f, 0.f, 0.f};
    float a2[4] = {0.f, 0.f, 0.f, 0.f};
    float axy[4] = {0.f, 0.f, 0.f, 0.f};
    float ad[4] = {0.f, 0.f, 0.f, 0.f};
#pragma unroll
    for (int q = 0; q < NC; ++q) {
      float4 vx4 = *(const float4*)(bx + 4 * q);
      float4 vy4 = *(const float4*)(by + 4 * q);
#pragma unroll
      for (int u = 0; u < 4; ++u) {
        const int jj = 4 * q + u - D;  // tap position rel. window start
        float vx = (&vx4.x)[u], vy = (&vy4.x)[u];
        float sq = fmaf(vy, vy, vx * vx);
        float pxy = vx * vy;
        float dd = LAST ? fabsf(vx - vy) : 0.f;
#pragma unroll
        for (int o = 0; o < 4; ++o) {
          if (o <= jj && jj - o < T) {  // compile-time predicate
            float g = gs[jj - o];
            ax[o] = fmaf(g, vx, ax[o]);
            ay[o] = fmaf(g, vy, ay[o]);
            a2[o] = fmaf(g, sq, a2[o]);
            axy[o] = fmaf(g, pxy, axy[o]);
            if (LAST) ad[o] = fmaf(g, dd, ad[o]);
          }
        }
      }
    }
    const int off = pr * HBS + c0;  // 16B-aligned
    *(float4*)(sm.hb[0] + off) = make_float4(ax[0], ax[1], ax[2], ax[3]);
    *(float4*)(sm.hb[1] + off) = make_float4(ay[0], ay[1], ay[2], ay[3]);
    *(float4*)(sm.hb[2] + off) = make_float4(a2[0], a2[1], a2[2], a2[3]);
    *(float4*)(sm.hb[3] + off) = make_float4(axy[0], axy[1], axy[2], axy[3]);
    if (LAST)
      *(float4*)(sm.hb[4] + off) = make_float4(ad[0], ad[1], ad[2], ad[3]);
  }
  __syncthreads();  // B2: hb ready

  // ---- V: per-map column conv, b128 streams ----
  float acc[8][4];
  const int m = tid >> 5;
  const int r0 = ((tid & 31) >> 3) << 3;
  const int c0v = (tid & 7) << 2;
  const bool vact = tid < NMAP * 32;
  if (vact) {
#pragma unroll
    for (int k = 0; k < 8; ++k)
#pragma unroll
      for (int j = 0; j < 4; ++j) acc[k][j] = 0.f;
    const float* hbase = sm.hb[m] + (16 - R + r0) * HBS + c0v;
#pragma unroll
    for (int jj = 0; jj < 2 * R + 8; ++jj) {
      float4 v = *(const float4*)(hbase + jj * HBS);
#pragma unroll
      for (int k = 0; k < 8; ++k) {
        if (k <= jj && jj - k <= 2 * R) {
          float g = gs[jj - k];
          acc[k][0] = fmaf(g, v.x, acc[k][0]);
          acc[k][1] = fmaf(g, v.y, acc[k][1]);
          acc[k][2] = fmaf(g, v.z, acc[k][2]);
          acc[k][3] = fmaf(g, v.w, acc[k][3]);
        }
      }
    }
  }
  __syncthreads();  // B3: all V reads of hb done
  if (vact) {
#pragma unroll
    for (int k = 0; k < 8; ++k)
      *(float4*)(sm.hb[m] + (r0 + k) * HBS + c0v) =
          make_float4(acc[k][0], acc[k][1], acc[k][2], acc[k][3]);
  }
  __syncthreads();  // B4: results in hb rows 0..31

  // ---- combine: fixed thread->pixel map across sigmas ----
  if (tid < 128) {
    const int c = tid & 31;
    const int rr0 = (tid >> 5) << 3;
#pragma unroll
    for (int k = 0; k < 8; ++k) {
      const int off = (rr0 + k) * HBS + c;
      float mux = sm.hb[0][off], muy = sm.hb[1][off];
      float m2 = sm.hb[2][off], mxy = sm.hb[3][off];
      float mux2 = mux * mux, muy2 = muy * muy, muxy = mux * muy;
      float cs = (2.f * (mxy - muxy) + kC2) / ((m2 - mux2 - muy2) + kC2);
      Pcs[k] *= cs;
      if (LAST) {
        lumP[k] = ((2.f * muxy + kC1) / (mux2 + muy2 + kC1)) * Pcs[k];
        l1v[k] = sm.hb[4][off];
      }
    }
  }
}

__global__ __launch_bounds__(256, 2) void msssim_l1_kernel(
    const float* __restrict__ x, const float* __restrict__ y,
    const float* __restrict__ gm, float* __restrict__ out) {
  __shared__ Smem sm;
  const int tid = threadIdx.x;

  // 1D taps: mask = outer(g,g) -> g[j] = m[16][j] / sqrt(m[16][16])
  if (tid < 165) {
    int s = tid / 33;
    int j = tid - s * 33;
    float c = gm[s * 1089 + 16 * 33 + 16];
    sm.g1[tid] = gm[s * 1089 + 16 * 33 + j] * rsqrtf(c);
  }

  // 64x64 halo patches, zero-padded, float4 (16B-aligned: SXS=68)
  const float* xb = x + blockIdx.z * (512 * 512);
  const float* yb = y + blockIdx.z * (512 * 512);
  const int rb = blockIdx.y * 32 - 16;
  const int cb = blockIdx.x * 32 - 16;
  for (int f = tid; f < 1024; f += 256) {
    int pr = f >> 4;
    int pc = (f & 15) << 2;
    int gr = rb + pr, gc = cb + pc;
    float4 vx = make_float4(0.f, 0.f, 0.f, 0.f);
    float4 vy = vx;
    if (gr >= 0 && gr < 512 && gc >= 0 && gc < 512) {
      vx = *(const float4*)(xb + gr * 512 + gc);
      vy = *(const float4*)(yb + gr * 512 + gc);
    }
    *(float4*)(sm.sx + pr * SXS + pc) = vx;
    *(float4*)(sm.sy + pr * SXS + pc) = vy;
  }

  float Pcs[8], lumP[8], l1v[8];
#pragma unroll
  for (int k = 0; k < 8; ++k) {
    Pcs[k] = 1.f;
    lumP[k] = 0.f;
    l1v[k] = 0.f;
  }

  // truncated radii: tails < e^-12 relative, negligible vs 0.137 threshold
  process_sigma<3, false>(sm, 0, tid, Pcs, lumP, l1v);
  process_sigma<5, false>(sm, 1, tid, Pcs, lumP, l1v);
  process_sigma<10, false>(sm, 2, tid, Pcs, lumP, l1v);
  process_sigma<16, false>(sm, 3, tid, Pcs, lumP, l1v);
  process_sigma<16, true>(sm, 4, tid, Pcs, lumP, l1v);

  // loss_mix = alpha*(1 - lum*PIcs) + (1-alpha)*gaussian_l1 ; out = 20*mean
  float lsum = 0.f;
  if (tid < 128) {
#pragma unroll
    for (int k = 0; k < 8; ++k)
      lsum += kAlpha * (1.f - lumP[k]) + (1.f - kAlpha) * l1v[k];
  }
#pragma unroll
  for (int off = 32; off > 0; off >>= 1) lsum += __shfl_down(lsum, off, 64);
  if ((tid & 63) == 0) sm.red[tid >> 6] = lsum;
  __syncthreads();
  if (tid == 0) {
    float t = sm.red[0] + sm.red[1] + sm.red[2] + sm.red[3];
    atomicAdd(out, t * (20.f / (16.f * 512.f * 512.f)));
  }
}

}  // namespace

extern "C" void kernel_launch(void* const* d_in, const int* in_sizes, int n_in,
                              void* d_out, int out_size, void* d_ws,
                              size_t ws_size, hipStream_t stream) {
  (void)in_sizes;
  (void)n_in;
  (void)d_ws;
  (void)ws_size;
  (void)out_size;
  const float* x = (const float*)d_in[0];
  const float* y = (const float*)d_in[1];
  const float* gm = (const float*)d_in[2];
  float* out = (float*)d_out;
  hipMemsetAsync(out, 0, sizeof(float), stream);
  dim3 grid(16, 16, 16);
  msssim_l1_kernel<<<grid, dim3(256), 0, stream>>>(x, y, gm, out);
}

// Round 4
// 303.669 us; speedup vs baseline: 1.1754x; 1.1754x over previous
//
#include <hip/hip_runtime.h>

namespace {

constexpr float kAlpha = 0.025f;
constexpr float kC1 = 1.0e-4f;  // (0.01*1)^2
constexpr float kC2 = 9.0e-4f;  // (0.03*1)^2

constexpr int SXS = 65;  // patch row stride: bank shift 1/row, scalar streams
constexpr int HBS = 33;  // hb row stride: bank = pr+col mod 32, conflict-free

// LDS: 2*64*65*4 = 33.3 KB patches + 5*64*33*4 = 42.2 KB hb + taps ~= 76.2 KB
// -> 2 blocks/CU (8 waves)
struct Smem {
  float sx[64 * SXS];
  float sy[64 * SXS];
  float hb[5][64 * HBS];  // maps: 0=x, 1=y, 2=x^2+y^2, 3=xy, 4=|x-y| (last)
  float g1[5 * 33];
  float red[4];
};

__device__ __forceinline__ float rfl(float v) {
  return __uint_as_float(__builtin_amdgcn_readfirstlane(__float_as_uint(v)));
}

// streaming column conv: 8 outputs from 2R+8 scalar reads (stride HBS)
template <int R>
__device__ __forceinline__ void vconv(const float* hbase, const float* gs,
                                      float acc[8]) {
#pragma unroll
  for (int k = 0; k < 8; ++k) acc[k] = 0.f;
#pragma unroll
  for (int jj = 0; jj < 2 * R + 8; ++jj) {
    float v = hbase[jj * HBS];
#pragma unroll
    for (int k = 0; k < 8; ++k) {
      if (k <= jj && jj - k <= 2 * R) acc[k] = fmaf(gs[jj - k], v, acc[k]);
    }
  }
}

// One sigma.
//  H (256 thr): streaming row conv, 4 output cols/item, scalar LDS.
//  V (256 thr): thread = (mapgroup=tid>>7, 8-row strip, col); 2(3) maps each,
//               results written back into hb rows 0..31 after B3.
//  C (128 thr): fixed thread->pixel map across sigmas, updates Pcs/lum/l1.
template <int R, bool LAST>
__device__ __forceinline__ void process_sigma(Smem& sm, int s, int tid,
                                              float Pcs[8], float lumP[8],
                                              float l1v[8]) {
  constexpr int T = 2 * R + 1;
  __syncthreads();  // B1: prev combine reads done; g1/patch ready (sigma 0)

  float gs[T];  // wave-uniform -> SGPRs
  {
    const float* gb = sm.g1 + s * 33 + (16 - R);
#pragma unroll
    for (int j = 0; j < T; ++j) gs[j] = rfl(gb[j]);
  }

  // ---- H: rows [16-R, 48+R), 32 cols, scalar streamed windows ----
  constexpr int ROWS = 32 + 2 * R;
  for (int idx = tid; idx < ROWS * 8; idx += 256) {
    const int pr = (16 - R) + (idx >> 3);
    const int c0 = (idx & 7) << 2;
    const float* bx = sm.sx + pr * SXS + c0 + (16 - R);
    const float* by = sm.sy + pr * SXS + c0 + (16 - R);
    float ax[4] = {0.f, 0.f, 0.f, 0.f};
    float ay[4] = {0.f, 0.f, 0.f, 0.f};
    float a2[4] = {0.f, 0.f, 0.f, 0.f};
    float axy[4] = {0.f, 0.f, 0.f, 0.f};
    float ad[4] = {0.f, 0.f, 0.f, 0.f};
#pragma unroll
    for (int jj = 0; jj < T + 3; ++jj) {
      float vx = bx[jj], vy = by[jj];
      float sq = fmaf(vy, vy, vx * vx);
      float pxy = vx * vy;
      float dd = LAST ? fabsf(vx - vy) : 0.f;
#pragma unroll
      for (int o = 0; o < 4; ++o) {
        if (o <= jj && jj - o < T) {  // compile-time predicate
          float g = gs[jj - o];
          ax[o] = fmaf(g, vx, ax[o]);
          ay[o] = fmaf(g, vy, ay[o]);
          a2[o] = fmaf(g, sq, a2[o]);
          axy[o] = fmaf(g, pxy, axy[o]);
          if (LAST) ad[o] = fmaf(g, dd, ad[o]);
        }
      }
    }
    const int off = pr * HBS + c0;
#pragma unroll
    for (int o = 0; o < 4; ++o) {
      sm.hb[0][off + o] = ax[o];
      sm.hb[1][off + o] = ay[o];
      sm.hb[2][off + o] = a2[o];
      sm.hb[3][off + o] = axy[o];
      if (LAST) sm.hb[4][off + o] = ad[o];
    }
  }
  __syncthreads();  // B2: hb ready

  // ---- V: all 256 threads, 2 maps each (mapgroup 1 adds |x-y| at LAST) ----
  const int c = tid & 31;
  const int r0 = ((tid >> 5) & 3) << 3;
  const int mg = tid >> 7;  // wave-uniform
  const int m0 = mg << 1;
  float acc0[8], acc1[8], acc4[8];
  const int rbase = (16 - R + r0) * HBS + c;
  vconv<R>(sm.hb[m0] + rbase, gs, acc0);
  vconv<R>(sm.hb[m0 + 1] + rbase, gs, acc1);
  if (LAST && mg == 1) vconv<R>(sm.hb[4] + rbase, gs, acc4);
  __syncthreads();  // B3: all V reads of hb done
#pragma unroll
  for (int k = 0; k < 8; ++k) {
    const int wo = (r0 + k) * HBS + c;
    sm.hb[m0][wo] = acc0[k];
    sm.hb[m0 + 1][wo] = acc1[k];
    if (LAST && mg == 1) sm.hb[4][wo] = acc4[k];
  }
  __syncthreads();  // B4: results in hb rows 0..31

  // ---- combine: fixed thread->pixel map across sigmas ----
  if (tid < 128) {
    const int cc = tid & 31;
    const int rr0 = (tid >> 5) << 3;
#pragma unroll
    for (int k = 0; k < 8; ++k) {
      const int off = (rr0 + k) * HBS + cc;
      float mux = sm.hb[0][off], muy = sm.hb[1][off];
      float m2 = sm.hb[2][off], mxy = sm.hb[3][off];
      float mux2 = mux * mux, muy2 = muy * muy, muxy = mux * muy;
      float cs = (2.f * (mxy - muxy) + kC2) / ((m2 - mux2 - muy2) + kC2);
      Pcs[k] *= cs;
      if (LAST) {
        lumP[k] = ((2.f * muxy + kC1) / (mux2 + muy2 + kC1)) * Pcs[k];
        l1v[k] = sm.hb[4][off];
      }
    }
  }
}

__global__ __launch_bounds__(256, 2) void msssim_l1_kernel(
    const float* __restrict__ x, const float* __restrict__ y,
    const float* __restrict__ gm, float* __restrict__ out) {
  __shared__ Smem sm;
  const int tid = threadIdx.x;

  // 1D taps: mask = outer(g,g) -> g[j] = m[16][j] / sqrt(m[16][16])
  if (tid < 165) {
    int s = tid / 33;
    int j = tid - s * 33;
    float c = gm[s * 1089 + 16 * 33 + 16];
    sm.g1[tid] = gm[s * 1089 + 16 * 33 + j] * rsqrtf(c);
  }

  // 64x64 halo patches, zero-padded; scalar LDS stores (2-way max = free)
  const float* xb = x + blockIdx.z * (512 * 512);
  const float* yb = y + blockIdx.z * (512 * 512);
  const int rb = blockIdx.y * 32 - 16;
  const int cb = blockIdx.x * 32 - 16;
  for (int f = tid; f < 1024; f += 256) {
    int pr = f >> 4;
    int pc = (f & 15) << 2;
    int gr = rb + pr, gc = cb + pc;
    float4 vx = make_float4(0.f, 0.f, 0.f, 0.f);
    float4 vy = vx;
    if (gr >= 0 && gr < 512 && gc >= 0 && gc < 512) {
      vx = *(const float4*)(xb + gr * 512 + gc);
      vy = *(const float4*)(yb + gr * 512 + gc);
    }
    int a = pr * SXS + pc;
    sm.sx[a + 0] = vx.x; sm.sx[a + 1] = vx.y;
    sm.sx[a + 2] = vx.z; sm.sx[a + 3] = vx.w;
    sm.sy[a + 0] = vy.x; sm.sy[a + 1] = vy.y;
    sm.sy[a + 2] = vy.z; sm.sy[a + 3] = vy.w;
  }

  float Pcs[8], lumP[8], l1v[8];
#pragma unroll
  for (int k = 0; k < 8; ++k) {
    Pcs[k] = 1.f;
    lumP[k] = 0.f;
    l1v[k] = 0.f;
  }

  // truncated radii: tails < e^-12 relative, negligible vs 0.137 threshold
  process_sigma<3, false>(sm, 0, tid, Pcs, lumP, l1v);
  process_sigma<5, false>(sm, 1, tid, Pcs, lumP, l1v);
  process_sigma<10, false>(sm, 2, tid, Pcs, lumP, l1v);
  process_sigma<16, false>(sm, 3, tid, Pcs, lumP, l1v);
  process_sigma<16, true>(sm, 4, tid, Pcs, lumP, l1v);

  // loss_mix = alpha*(1 - lum*PIcs) + (1-alpha)*gaussian_l1 ; out = 20*mean
  float lsum = 0.f;
  if (tid < 128) {
#pragma unroll
    for (int k = 0; k < 8; ++k)
      lsum += kAlpha * (1.f - lumP[k]) + (1.f - kAlpha) * l1v[k];
  }
#pragma unroll
  for (int off = 32; off > 0; off >>= 1) lsum += __shfl_down(lsum, off, 64);
  if ((tid & 63) == 0) sm.red[tid >> 6] = lsum;
  __syncthreads();
  if (tid == 0) {
    float t = sm.red[0] + sm.red[1] + sm.red[2] + sm.red[3];
    atomicAdd(out, t * (20.f / (16.f * 512.f * 512.f)));
  }
}

}  // namespace

extern "C" void kernel_launch(void* const* d_in, const int* in_sizes, int n_in,
                              void* d_out, int out_size, void* d_ws,
                              size_t ws_size, hipStream_t stream) {
  (void)in_sizes;
  (void)n_in;
  (void)d_ws;
  (void)ws_size;
  (void)out_size;
  const float* x = (const float*)d_in[0];
  const float* y = (const float*)d_in[1];
  const float* gm = (const float*)d_in[2];
  float* out = (float*)d_out;
  hipMemsetAsync(out, 0, sizeof(float), stream);
  dim3 grid(16, 16, 16);
  msssim_l1_kernel<<<grid, dim3(256), 0, stream>>>(x, y, gm, out);
}